// Round 4
// baseline (759.166 us; speedup 1.0000x reference)
//
#include <hip/hip_runtime.h>

typedef __attribute__((ext_vector_type(8))) __bf16 bf16x8;
typedef __attribute__((ext_vector_type(4))) float f32x4;

__device__ __forceinline__ float bf2f(unsigned int u) {
    union { unsigned int u; float f; } v; v.u = u << 16; return v.f;
}
__device__ __forceinline__ unsigned short f2bf(float f) {
    union { float f; unsigned int u; } v; v.f = f;
    unsigned int r = v.u + 0x7fffu + ((v.u >> 16) & 1u);
    return (unsigned short)(r >> 16);
}
__device__ __forceinline__ unsigned int pack2(float a, float b) {
    return (unsigned int)f2bf(a) | ((unsigned int)f2bf(b) << 16);
}

// ---------------------------------------------------------------------------
// GEMM: C = A(lda) @ B[N,K]^T (+bias). A/B fp32 (A32/B32=true, converted to
// bf16 during staging) or bf16. C fp32 (C32) or bf16. fp32 accumulate.
// 128x128 tile, 4 waves 2x2, BK=32, plain register staging, LDS rows padded
// to 40 shorts. TRANS_C: write C^T[col*ldc+row].
// ---------------------------------------------------------------------------
template <bool A32, bool B32, bool C32, bool HAS_BIAS, bool TRANS_C>
__global__ __launch_bounds__(256, 2)
void gemm_bt(const void* __restrict__ Ap, const void* __restrict__ Bp,
             const float* __restrict__ bias, void* __restrict__ Cp,
             int M, int N, int K, int lda, int ldc) {
    __shared__ __align__(16) unsigned short As[128 * 40];
    __shared__ __align__(16) unsigned short Bs[128 * 40];
    const int t = threadIdx.x, lane = t & 63;
    const int wm = t >> 7, wn = (t >> 6) & 1;
    const int m0 = blockIdx.x * 128, n0 = blockIdx.y * 128;
    const int lr = lane & 15, kc = lane >> 4;
    f32x4 acc[4][4] = {};

    for (int k0 = 0; k0 < K; k0 += 32) {
        float4 ra32[4], rb32[4];
        bf16x8 ra16[2], rb16[2];
        if constexpr (A32) {
            const float* A = (const float*)Ap;
#pragma unroll
            for (int i = 0; i < 4; ++i) {
                int idx = i * 256 + t, row = idx >> 3, c4 = idx & 7;
                ra32[i] = *(const float4*)&A[(size_t)(m0 + row) * lda + k0 + c4 * 4];
            }
        } else {
            const unsigned short* A = (const unsigned short*)Ap;
#pragma unroll
            for (int i = 0; i < 2; ++i) {
                int idx = i * 256 + t, row = idx >> 2, c8 = idx & 3;
                ra16[i] = *(const bf16x8*)&A[(size_t)(m0 + row) * lda + k0 + c8 * 8];
            }
        }
        if constexpr (B32) {
            const float* B = (const float*)Bp;
#pragma unroll
            for (int i = 0; i < 4; ++i) {
                int idx = i * 256 + t, row = idx >> 3, c4 = idx & 7;
                rb32[i] = *(const float4*)&B[(size_t)(n0 + row) * K + k0 + c4 * 4];
            }
        } else {
            const unsigned short* B = (const unsigned short*)Bp;
#pragma unroll
            for (int i = 0; i < 2; ++i) {
                int idx = i * 256 + t, row = idx >> 2, c8 = idx & 3;
                rb16[i] = *(const bf16x8*)&B[(size_t)(n0 + row) * K + k0 + c8 * 8];
            }
        }
        __syncthreads();   // all waves done reading previous tile's LDS
        if constexpr (A32) {
#pragma unroll
            for (int i = 0; i < 4; ++i) {
                int idx = i * 256 + t, row = idx >> 3, c4 = idx & 7;
                uint2 p = { pack2(ra32[i].x, ra32[i].y), pack2(ra32[i].z, ra32[i].w) };
                *(uint2*)&As[row * 40 + c4 * 4] = p;
            }
        } else {
#pragma unroll
            for (int i = 0; i < 2; ++i) {
                int idx = i * 256 + t, row = idx >> 2, c8 = idx & 3;
                *(bf16x8*)&As[row * 40 + c8 * 8] = ra16[i];
            }
        }
        if constexpr (B32) {
#pragma unroll
            for (int i = 0; i < 4; ++i) {
                int idx = i * 256 + t, row = idx >> 3, c4 = idx & 7;
                uint2 p = { pack2(rb32[i].x, rb32[i].y), pack2(rb32[i].z, rb32[i].w) };
                *(uint2*)&Bs[row * 40 + c4 * 4] = p;
            }
        } else {
#pragma unroll
            for (int i = 0; i < 2; ++i) {
                int idx = i * 256 + t, row = idx >> 2, c8 = idx & 3;
                *(bf16x8*)&Bs[row * 40 + c8 * 8] = rb16[i];
            }
        }
        __syncthreads();
        bf16x8 af[4], bfr[4];
#pragma unroll
        for (int i = 0; i < 4; ++i) {
            af[i]  = *(const bf16x8*)&As[(wm * 64 + i * 16 + lr) * 40 + kc * 8];
            bfr[i] = *(const bf16x8*)&Bs[(wn * 64 + i * 16 + lr) * 40 + kc * 8];
        }
#pragma unroll
        for (int mi = 0; mi < 4; ++mi)
#pragma unroll
            for (int ni = 0; ni < 4; ++ni)
                acc[mi][ni] = __builtin_amdgcn_mfma_f32_16x16x32_bf16(af[mi], bfr[ni], acc[mi][ni], 0, 0, 0);
    }
    const int rb0 = kc * 4;   // C/D: col=lane&15, row=(lane>>4)*4+reg  [m89]
#pragma unroll
    for (int mi = 0; mi < 4; ++mi) {
#pragma unroll
        for (int ni = 0; ni < 4; ++ni) {
            int col = n0 + wn * 64 + ni * 16 + lr;
            float badd = HAS_BIAS ? bias[col] : 0.0f;
#pragma unroll
            for (int r = 0; r < 4; ++r) {
                int row = m0 + wm * 64 + mi * 16 + rb0 + r;
                size_t off = TRANS_C ? ((size_t)col * ldc + row) : ((size_t)row * ldc + col);
                if (C32) ((float*)Cp)[off] = acc[mi][ni][r] + badd;
                else     ((unsigned short*)Cp)[off] = f2bf(acc[mi][ni][r] + badd);
            }
        }
    }
}

// ---------------------------------------------------------------------------
// In-place RMSNorm + RoPE on qk[2048][6144] bf16 (q cols 0..3071, k 3072+).
// pe/scales are fp32. One wave per (tensor, head, l); lane i owns d-pair.
// ---------------------------------------------------------------------------
__global__ __launch_bounds__(256)
void norm_rope(unsigned short* __restrict__ qk, const float* __restrict__ pe,
               const float* __restrict__ q_scale, const float* __restrict__ k_scale) {
    const int wid = threadIdx.x >> 6, lane = threadIdx.x & 63;
    int pid = blockIdx.x * 4 + wid;          // [0, 2*24*2048)
    const int isK = pid >= 49152;
    int p2 = isK ? pid - 49152 : pid;
    const int h = p2 >> 11, l = p2 & 2047;

    unsigned short* src = qk + (size_t)l * 6144 + (isK ? 3072 : 0) + h * 128 + lane * 2;
    unsigned int xu = *(const unsigned int*)src;
    float x0 = bf2f(xu & 0xffffu), x1 = bf2f(xu >> 16);
    float ss = x0 * x0 + x1 * x1;
#pragma unroll
    for (int off = 32; off >= 1; off >>= 1) ss += __shfl_xor(ss, off);
    float rr = rsqrtf(ss * (1.0f / 128.0f) + 1e-6f);

    const float* sc = isK ? k_scale : q_scale;
    float2 s2 = *(const float2*)(sc + lane * 2);
    float y0 = x0 * rr * s2.x;
    float y1 = x1 * rr * s2.y;

    float4 p4 = *(const float4*)(pe + ((size_t)l * 64 + lane) * 4);
    float o0 = p4.x * y0 + p4.y * y1;   // [[r00,r01],[r10,r11]]
    float o1 = p4.z * y0 + p4.w * y1;

    *(unsigned int*)src = pack2(o0, o1);
}

// ---------------------------------------------------------------------------
// Flash attention, plain staging. Block = 1 head x 128 q rows (4 waves x 32).
// Reads q/k from qk bf16 (stride 6144), V^T from vt[3072][2048] bf16; writes
// output in-place over this block's own q region (sole reader = writer).
// ---------------------------------------------------------------------------
__global__ __launch_bounds__(256, 2)
void attn(unsigned short* __restrict__ qk, const unsigned short* __restrict__ vt) {
    __shared__ __align__(16) unsigned short Ks[64 * 136];
    __shared__ __align__(16) unsigned short Vs[128 * 72];
    __shared__ __align__(16) unsigned short Ps[4 * 32 * 72];
    const int t = threadIdx.x, lane = t & 63, w = t >> 6;
    const int h = blockIdx.y, q0 = blockIdx.x * 128;
    const int lr = lane & 15, kc = lane >> 4;
    const float scale = 0.08838834764831845f;  // 1/sqrt(128)

    bf16x8 aq[2][4];
#pragma unroll
    for (int mf = 0; mf < 2; ++mf)
#pragma unroll
        for (int ks = 0; ks < 4; ++ks)
            aq[mf][ks] = *(const bf16x8*)&qk[(size_t)(q0 + w * 32 + mf * 16 + lr) * 6144 + h * 128 + ks * 32 + kc * 8];

    f32x4 o[2][8] = {};
    float mst[2][4], lst[2][4];
#pragma unroll
    for (int mf = 0; mf < 2; ++mf)
#pragma unroll
        for (int r = 0; r < 4; ++r) { mst[mf][r] = -1e30f; lst[mf][r] = 0.0f; }

    unsigned short* Pw = &Ps[w * 32 * 72];

    for (int kb = 0; kb < 2048; kb += 64) {
        bf16x8 rk[4], rv[4];
#pragma unroll
        for (int i = 0; i < 4; ++i) {
            int idx = i * 256 + t;
            { int row = idx >> 4, c8 = idx & 15;
              rk[i] = *(const bf16x8*)&qk[(size_t)(kb + row) * 6144 + 3072 + h * 128 + c8 * 8]; }
            { int row = idx >> 3, c8 = idx & 7;
              rv[i] = *(const bf16x8*)&vt[(size_t)(h * 128 + row) * 2048 + kb + c8 * 8]; }
        }
        __syncthreads();
#pragma unroll
        for (int i = 0; i < 4; ++i) {
            int idx = i * 256 + t;
            { int row = idx >> 4, c8 = idx & 15; *(bf16x8*)&Ks[row * 136 + c8 * 8] = rk[i]; }
            { int row = idx >> 3, c8 = idx & 7;  *(bf16x8*)&Vs[row * 72 + c8 * 8] = rv[i]; }
        }
        __syncthreads();

        // S = Q K^T
        f32x4 s[2][4] = {};
#pragma unroll
        for (int nt = 0; nt < 4; ++nt) {
            int rkr = nt * 16 + lr;
#pragma unroll
            for (int ks = 0; ks < 4; ++ks) {
                bf16x8 bk = *(const bf16x8*)&Ks[rkr * 136 + (ks * 4 + kc) * 8];
#pragma unroll
                for (int mf = 0; mf < 2; ++mf)
                    s[mf][nt] = __builtin_amdgcn_mfma_f32_16x16x32_bf16(aq[mf][ks], bk, s[mf][nt], 0, 0, 0);
            }
        }
#pragma unroll
        for (int mf = 0; mf < 2; ++mf)
#pragma unroll
            for (int nt = 0; nt < 4; ++nt)
#pragma unroll
                for (int r = 0; r < 4; ++r) s[mf][nt][r] *= scale;

        // online softmax (row = kc*4+r inside each 16-row m-frag)
#pragma unroll
        for (int mf = 0; mf < 2; ++mf) {
#pragma unroll
            for (int r = 0; r < 4; ++r) {
                float vmax = fmaxf(fmaxf(s[mf][0][r], s[mf][1][r]), fmaxf(s[mf][2][r], s[mf][3][r]));
#pragma unroll
                for (int off = 8; off >= 1; off >>= 1) vmax = fmaxf(vmax, __shfl_xor(vmax, off));
                float mn = fmaxf(mst[mf][r], vmax);
                float al = __expf(mst[mf][r] - mn);
                mst[mf][r] = mn;
                float ps = 0.0f;
#pragma unroll
                for (int nt = 0; nt < 4; ++nt) {
                    float p = __expf(s[mf][nt][r] - mn);
                    s[mf][nt][r] = p;
                    ps += p;
                }
#pragma unroll
                for (int off = 8; off >= 1; off >>= 1) ps += __shfl_xor(ps, off);
                lst[mf][r] = lst[mf][r] * al + ps;
#pragma unroll
                for (int dt = 0; dt < 8; ++dt) o[mf][dt][r] *= al;
            }
        }

        // P (C-layout) -> per-wave LDS [32 q][64 kk] (pad 72)
#pragma unroll
        for (int mf = 0; mf < 2; ++mf)
#pragma unroll
            for (int nt = 0; nt < 4; ++nt)
#pragma unroll
                for (int r = 0; r < 4; ++r)
                    Pw[(mf * 16 + kc * 4 + r) * 72 + nt * 16 + lr] = f2bf(s[mf][nt][r]);

        // O += P @ V  (A = P[q][kk], B = Vt[d][kk])
#pragma unroll
        for (int ks2 = 0; ks2 < 2; ++ks2) {
            bf16x8 ap[2];
#pragma unroll
            for (int mf = 0; mf < 2; ++mf)
                ap[mf] = *(const bf16x8*)&Pw[(mf * 16 + lr) * 72 + (ks2 * 4 + kc) * 8];
#pragma unroll
            for (int dt = 0; dt < 8; ++dt) {
                bf16x8 bv = *(const bf16x8*)&Vs[(dt * 16 + lr) * 72 + (ks2 * 4 + kc) * 8];
#pragma unroll
                for (int mf = 0; mf < 2; ++mf)
                    o[mf][dt] = __builtin_amdgcn_mfma_f32_16x16x32_bf16(ap[mf], bv, o[mf][dt], 0, 0, 0);
            }
        }
        __syncthreads();
    }

    // write attention output over this block's own q region: qk[l][h*128+d]
#pragma unroll
    for (int mf = 0; mf < 2; ++mf)
#pragma unroll
        for (int dt = 0; dt < 8; ++dt)
#pragma unroll
            for (int r = 0; r < 4; ++r) {
                int row = q0 + w * 32 + mf * 16 + kc * 4 + r;
                qk[(size_t)row * 6144 + h * 128 + dt * 16 + lr] = f2bf(o[mf][dt][r] / lst[mf][r]);
            }
}

// Sentinel: d_out = all 2.0f -> distinctive absmax ~2.19 if ws too small.
__global__ void fill_two(float* p, int n) {
    int i = blockIdx.x * 256 + threadIdx.x;
    if (i < n) p[i] = 2.0f;
}

// ---------------------------------------------------------------------------
// Dtype model: ALL inputs fp32, output fp32 (per reference setup_inputs).
// ws plan (shorts): qk[2048][6144] bf16 @ 0 (q|k in-place; attn out over q),
// vt[3072][2048] bf16 @ 12582912. Peak 18874368 shorts = 36 MiB.
// fp32->bf16 weight/x conversion happens inside GEMM staging (no copies).
// ---------------------------------------------------------------------------
extern "C" void kernel_launch(void* const* d_in, const int* in_sizes, int n_in,
                              void* d_out, int out_size, void* d_ws, size_t ws_size,
                              hipStream_t stream) {
    const float* x       = (const float*)d_in[0];  // [2048,3072]
    const float* pe      = (const float*)d_in[1];  // [2048,64,2,2]
    const float* w_qkv   = (const float*)d_in[2];  // [9216,3072]
    const float* q_scale = (const float*)d_in[3];  // [128]
    const float* k_scale = (const float*)d_in[4];  // [128]
    const float* w_proj  = (const float*)d_in[5];  // [3072,3072]
    const float* b_proj  = (const float*)d_in[6];  // [3072]
    float* out = (float*)d_out;

    if (ws_size < 37748736ull) {   // 36 MiB needed
        fill_two<<<(6291456 + 255) / 256, 256, 0, stream>>>(out, 6291456);
        return;
    }
    unsigned short* qk = (unsigned short*)d_ws;     // [2048][6144] bf16
    unsigned short* vt = qk + 12582912;             // [3072][2048] bf16

    // qk = bf16(x @ w_qkv[0:6144]^T)
    gemm_bt<true, true, false, false, false><<<dim3(16, 48), 256, 0, stream>>>(
        x, w_qkv, nullptr, qk, 2048, 6144, 3072, 3072, 6144);
    // in-place RMSNorm+RoPE on q,k
    norm_rope<<<24576, 256, 0, stream>>>(qk, pe, q_scale, k_scale);
    // vt = bf16((x @ w_qkv[6144:9216]^T)^T) via transposed epilogue
    gemm_bt<true, true, false, false, true><<<dim3(16, 24), 256, 0, stream>>>(
        x, w_qkv + (size_t)6144 * 3072, nullptr, vt, 2048, 3072, 3072, 3072, 2048);
    // attention; output lands in qk cols [0,3072)
    attn<<<dim3(16, 24), 256, 0, stream>>>(qk, vt);
    // out = attn_out @ w_proj^T + b_proj  (A = qk bf16, lda 6144; C fp32)
    gemm_bt<false, true, true, true, false><<<dim3(16, 24), 256, 0, stream>>>(
        qk, w_proj, b_proj, out, 2048, 3072, 3072, 6144, 3072);
}

// Round 6
// 605.205 us; speedup vs baseline: 1.2544x; 1.2544x over previous
//
#include <hip/hip_runtime.h>

typedef __attribute__((ext_vector_type(8))) __bf16 bf16x8;
typedef __attribute__((ext_vector_type(4))) float f32x4;

typedef __attribute__((address_space(1))) void gvoid;
typedef __attribute__((address_space(3))) void lvoid;

__device__ __forceinline__ float bf2f(unsigned int u) {
    union { unsigned int u; float f; } v; v.u = u << 16; return v.f;
}
__device__ __forceinline__ unsigned short f2bf(float f) {
    union { float f; unsigned int u; } v; v.f = f;
    unsigned int r = v.u + 0x7fffu + ((v.u >> 16) & 1u);
    return (unsigned short)(r >> 16);
}
__device__ __forceinline__ unsigned int pack2(float a, float b) {
    return (unsigned int)f2bf(a) | ((unsigned int)f2bf(b) << 16);
}
__device__ __forceinline__ void async16(const void* g, void* l) {
    __builtin_amdgcn_global_load_lds((gvoid*)g, (lvoid*)l, 16, 0, 0);
}
// 2^x via v_exp_f32 (native). __exp2f is NOT declared in this env's headers.
__device__ __forceinline__ float exp2f_hw(float x) {
    return __builtin_amdgcn_exp2f(x);
}

// ============================ FAST PATH ====================================

// fp32 -> bf16 bulk convert, 8 elems/thread.
__global__ __launch_bounds__(256)
void cvt_bf16(const float4* __restrict__ s, uint4* __restrict__ d, int n8) {
    int i = blockIdx.x * 256 + threadIdx.x;
    if (i >= n8) return;
    float4 a = s[2 * i], b = s[2 * i + 1];
    uint4 o;
    o.x = pack2(a.x, a.y); o.y = pack2(a.z, a.w);
    o.z = pack2(b.x, b.y); o.w = pack2(b.z, b.w);
    d[i] = o;
}

// m97-style bf16 GEMM core: 128x128 tile, BK=32, async16 staging with
// global-side XOR swizzle (gc = (c8 ^ ((row>>1)&3))*8), linear LDS.
// Reader swizzle matches; wave64 ds_read_b128 is bank-balanced (8/bank floor).
#define GEMM_CORE(A_, lda_, B_, ldb_, K_)                                        \
    __shared__ __align__(16) unsigned short As[4096];                            \
    __shared__ __align__(16) unsigned short Bs[4096];                            \
    const int t = threadIdx.x, lane = t & 63;                                    \
    const int wm = t >> 7, wn = (t >> 6) & 1;                                    \
    const int lr = lane & 15, kc = lane >> 4;                                    \
    f32x4 acc[4][4] = {};                                                        \
    for (int k0 = 0; k0 < (K_); k0 += 32) {                                      \
        _Pragma("unroll")                                                        \
        for (int i = 0; i < 2; ++i) {                                            \
            int e = (i * 256 + t) * 8;                                           \
            int row = e >> 5, c8 = (e >> 3) & 3;                                 \
            int gc = (c8 ^ ((row >> 1) & 3)) * 8;                                \
            async16(&(A_)[(size_t)(m0 + row) * (lda_) + k0 + gc], &As[e]);       \
            async16(&(B_)[(size_t)(n0 + row) * (ldb_) + k0 + gc], &Bs[e]);       \
        }                                                                        \
        __syncthreads();                                                         \
        bf16x8 af[4], bfr[4];                                                    \
        _Pragma("unroll")                                                        \
        for (int i = 0; i < 4; ++i) {                                            \
            int ra = wm * 64 + i * 16 + lr;                                      \
            int rb = wn * 64 + i * 16 + lr;                                      \
            af[i]  = *(const bf16x8*)&As[ra * 32 + ((kc ^ ((ra >> 1) & 3)) * 8)];\
            bfr[i] = *(const bf16x8*)&Bs[rb * 32 + ((kc ^ ((rb >> 1) & 3)) * 8)];\
        }                                                                        \
        _Pragma("unroll")                                                        \
        for (int mi = 0; mi < 4; ++mi)                                           \
            _Pragma("unroll")                                                    \
            for (int ni = 0; ni < 4; ++ni)                                       \
                acc[mi][ni] = __builtin_amdgcn_mfma_f32_16x16x32_bf16(           \
                    af[mi], bfr[ni], acc[mi][ni], 0, 0, 0);                      \
        __syncthreads();                                                         \
    }

// Fused QKV GEMM: A=xb[2048][3072], B=wqkvb[9216][3072].
// cols <6144 -> qk[row][col]; cols >=6144 -> vt[col-6144][row] (V transposed).
// grid (72 nblk, 16 mblk): same-n blocks land on one XCD (72 % 8 == 0).
__global__ __launch_bounds__(256, 2)
void gemm_qkv(const unsigned short* __restrict__ A, const unsigned short* __restrict__ B,
              unsigned short* __restrict__ qk, unsigned short* __restrict__ vt) {
    const int n0 = blockIdx.x * 128, m0 = blockIdx.y * 128;
    GEMM_CORE(A, 3072, B, 3072, 3072)
    const int rb0 = kc * 4;
#pragma unroll
    for (int mi = 0; mi < 4; ++mi)
#pragma unroll
        for (int ni = 0; ni < 4; ++ni) {
            int col = n0 + wn * 64 + ni * 16 + lr;
#pragma unroll
            for (int r = 0; r < 4; ++r) {
                int row = m0 + wm * 64 + mi * 16 + rb0 + r;
                unsigned short v = f2bf(acc[mi][ni][r]);
                if (col < 6144) qk[(size_t)row * 6144 + col] = v;
                else            vt[(size_t)(col - 6144) * 2048 + row] = v;
            }
        }
}

// Proj GEMM: A=qk(attn out, lda 6144), B=wprojb[3072][3072], fp32 out + bias.
__global__ __launch_bounds__(256, 2)
void gemm_proj(const unsigned short* __restrict__ A, const unsigned short* __restrict__ B,
               const float* __restrict__ bias, float* __restrict__ out) {
    const int n0 = blockIdx.x * 128, m0 = blockIdx.y * 128;
    GEMM_CORE(A, 6144, B, 3072, 3072)
    const int rb0 = kc * 4;
#pragma unroll
    for (int mi = 0; mi < 4; ++mi)
#pragma unroll
        for (int ni = 0; ni < 4; ++ni) {
            int col = n0 + wn * 64 + ni * 16 + lr;
            float badd = bias[col];
#pragma unroll
            for (int r = 0; r < 4; ++r) {
                int row = m0 + wm * 64 + mi * 16 + rb0 + r;
                out[(size_t)row * 3072 + col] = acc[mi][ni][r] + badd;
            }
        }
}

// Flash attention v2: block = 1 head x 64 q rows (4 waves x 16 rows).
// grid (24 heads, 32 qtiles) -> same-head blocks on one XCD (24 % 8 == 0).
// Bk=64; Ks/Vs async16-staged with global-side swizzle; per-wave swizzled Ps.
// LDS 40 KB -> 4 blocks/CU. exp2-domain online softmax.
__global__ __launch_bounds__(256)
void attn2(unsigned short* __restrict__ qk, const unsigned short* __restrict__ vt) {
    __shared__ __align__(16) unsigned short Ks[64 * 128];
    __shared__ __align__(16) unsigned short Vs[128 * 64];
    __shared__ __align__(16) unsigned short Ps[4 * 16 * 64];
    const int t = threadIdx.x, lane = t & 63, w = t >> 6;
    const int h = blockIdx.x, qblk = blockIdx.y * 64;
    const int lr = lane & 15, kc = lane >> 4;
    const float sc2 = 0.08838834764831845f * 1.4426950408889634f; // scale*log2e

    bf16x8 aq[4];
#pragma unroll
    for (int ks = 0; ks < 4; ++ks)
        aq[ks] = *(const bf16x8*)&qk[(size_t)(qblk + w * 16 + lr) * 6144 + h * 128 + ks * 32 + kc * 8];

    f32x4 o[8] = {};
    float mst[4], lst[4];
#pragma unroll
    for (int r = 0; r < 4; ++r) { mst[r] = -1e30f; lst[r] = 0.0f; }

    unsigned short* Pw = &Ps[w * 1024];

    for (int kb = 0; kb < 2048; kb += 64) {
#pragma unroll
        for (int i = 0; i < 4; ++i) {
            int e = (i * 256 + t) * 8;
            {   // K tile [64 keys][128 d]
                int row = e >> 7, c8 = (e >> 3) & 15;
                int gc = (c8 ^ (row & 15)) * 8;
                async16(&qk[(size_t)(kb + row) * 6144 + 3072 + h * 128 + gc], &Ks[e]);
            }
            {   // V^T tile [128 d][64 keys]
                int row = e >> 6, c8 = (e >> 3) & 7;
                int gc = (c8 ^ (row & 7)) * 8;
                async16(&vt[(size_t)(h * 128 + row) * 2048 + kb + gc], &Vs[e]);
            }
        }
        __syncthreads();

        // S = Q K^T  (C rows = q = kc*4+r, cols = key = nt*16+lr)
        f32x4 s[4] = {};
#pragma unroll
        for (int nt = 0; nt < 4; ++nt) {
            int rk = nt * 16 + lr;
#pragma unroll
            for (int ks = 0; ks < 4; ++ks) {
                int ck = ks * 4 + kc;
                bf16x8 bk = *(const bf16x8*)&Ks[rk * 128 + ((ck ^ (rk & 15)) * 8)];
                s[nt] = __builtin_amdgcn_mfma_f32_16x16x32_bf16(aq[ks], bk, s[nt], 0, 0, 0);
            }
        }

        // online softmax in exp2 domain
#pragma unroll
        for (int r = 0; r < 4; ++r) {
            float vmax = fmaxf(fmaxf(s[0][r], s[1][r]), fmaxf(s[2][r], s[3][r]));
#pragma unroll
            for (int off = 8; off >= 1; off >>= 1) vmax = fmaxf(vmax, __shfl_xor(vmax, off));
            float mn = fmaxf(mst[r], vmax);
            float al = exp2f_hw((mst[r] - mn) * sc2);
            mst[r] = mn;
            float ps = 0.0f;
#pragma unroll
            for (int nt = 0; nt < 4; ++nt) {
                float p = exp2f_hw((s[nt][r] - mn) * sc2);
                s[nt][r] = p;
                ps += p;
            }
#pragma unroll
            for (int off = 8; off >= 1; off >>= 1) ps += __shfl_xor(ps, off);
            lst[r] = lst[r] * al + ps;
#pragma unroll
            for (int dt = 0; dt < 8; ++dt) o[dt][r] *= al;
        }

        // P (C-layout) -> per-wave LDS [16 q][64 kk], chunk ^= (q&7)
#pragma unroll
        for (int nt = 0; nt < 4; ++nt) {
            int col = nt * 16 + lr;
            int chunk = col >> 3, cin = col & 7;
#pragma unroll
            for (int r = 0; r < 4; ++r) {
                int q = kc * 4 + r;
                Pw[q * 64 + ((chunk ^ (q & 7)) * 8 + cin)] = f2bf(s[nt][r]);
            }
        }

        // O += P @ V  (A = P[q][kk], B = Vt[d][kk])
#pragma unroll
        for (int ks2 = 0; ks2 < 2; ++ks2) {
            int ck = ks2 * 4 + kc;
            bf16x8 ap = *(const bf16x8*)&Pw[lr * 64 + ((ck ^ (lr & 7)) * 8)];
#pragma unroll
            for (int dt = 0; dt < 8; ++dt) {
                int rv = dt * 16 + lr;
                bf16x8 bv = *(const bf16x8*)&Vs[rv * 64 + ((ck ^ (rv & 7)) * 8)];
                o[dt] = __builtin_amdgcn_mfma_f32_16x16x32_bf16(ap, bv, o[dt], 0, 0, 0);
            }
        }
        __syncthreads();
    }

    // write output over this block's own q region
#pragma unroll
    for (int dt = 0; dt < 8; ++dt)
#pragma unroll
        for (int r = 0; r < 4; ++r) {
            int row = qblk + w * 16 + kc * 4 + r;
            qk[(size_t)row * 6144 + h * 128 + dt * 16 + lr] = f2bf(o[dt][r] / lst[r]);
        }
}

// ===================== SHARED (both paths) =================================

// In-place RMSNorm + RoPE on qk[2048][6144] bf16 (q cols 0..3071, k 3072+).
__global__ __launch_bounds__(256)
void norm_rope(unsigned short* __restrict__ qk, const float* __restrict__ pe,
               const float* __restrict__ q_scale, const float* __restrict__ k_scale) {
    const int wid = threadIdx.x >> 6, lane = threadIdx.x & 63;
    int pid = blockIdx.x * 4 + wid;
    const int isK = pid >= 49152;
    int p2 = isK ? pid - 49152 : pid;
    const int h = p2 >> 11, l = p2 & 2047;

    unsigned short* src = qk + (size_t)l * 6144 + (isK ? 3072 : 0) + h * 128 + lane * 2;
    unsigned int xu = *(const unsigned int*)src;
    float x0 = bf2f(xu & 0xffffu), x1 = bf2f(xu >> 16);
    float ss = x0 * x0 + x1 * x1;
#pragma unroll
    for (int off = 32; off >= 1; off >>= 1) ss += __shfl_xor(ss, off);
    float rr = rsqrtf(ss * (1.0f / 128.0f) + 1e-6f);

    const float* sc = isK ? k_scale : q_scale;
    float2 s2 = *(const float2*)(sc + lane * 2);
    float y0 = x0 * rr * s2.x;
    float y1 = x1 * rr * s2.y;

    float4 p4 = *(const float4*)(pe + ((size_t)l * 64 + lane) * 4);
    float o0 = p4.x * y0 + p4.y * y1;
    float o1 = p4.z * y0 + p4.w * y1;

    *(unsigned int*)src = pack2(o0, o1);
}

// ===================== SLOW PATH (round-4, proven) =========================

template <bool A32, bool B32, bool C32, bool HAS_BIAS, bool TRANS_C>
__global__ __launch_bounds__(256, 2)
void gemm_bt(const void* __restrict__ Ap, const void* __restrict__ Bp,
             const float* __restrict__ bias, void* __restrict__ Cp,
             int M, int N, int K, int lda, int ldc) {
    __shared__ __align__(16) unsigned short As[128 * 40];
    __shared__ __align__(16) unsigned short Bs[128 * 40];
    const int t = threadIdx.x, lane = t & 63;
    const int wm = t >> 7, wn = (t >> 6) & 1;
    const int m0 = blockIdx.x * 128, n0 = blockIdx.y * 128;
    const int lr = lane & 15, kc = lane >> 4;
    f32x4 acc[4][4] = {};

    for (int k0 = 0; k0 < K; k0 += 32) {
        float4 ra32[4], rb32[4];
        bf16x8 ra16[2], rb16[2];
        if constexpr (A32) {
            const float* A = (const float*)Ap;
#pragma unroll
            for (int i = 0; i < 4; ++i) {
                int idx = i * 256 + t, row = idx >> 3, c4 = idx & 7;
                ra32[i] = *(const float4*)&A[(size_t)(m0 + row) * lda + k0 + c4 * 4];
            }
        } else {
            const unsigned short* A = (const unsigned short*)Ap;
#pragma unroll
            for (int i = 0; i < 2; ++i) {
                int idx = i * 256 + t, row = idx >> 2, c8 = idx & 3;
                ra16[i] = *(const bf16x8*)&A[(size_t)(m0 + row) * lda + k0 + c8 * 8];
            }
        }
        if constexpr (B32) {
            const float* B = (const float*)Bp;
#pragma unroll
            for (int i = 0; i < 4; ++i) {
                int idx = i * 256 + t, row = idx >> 3, c4 = idx & 7;
                rb32[i] = *(const float4*)&B[(size_t)(n0 + row) * K + k0 + c4 * 4];
            }
        } else {
            const unsigned short* B = (const unsigned short*)Bp;
#pragma unroll
            for (int i = 0; i < 2; ++i) {
                int idx = i * 256 + t, row = idx >> 2, c8 = idx & 3;
                rb16[i] = *(const bf16x8*)&B[(size_t)(n0 + row) * K + k0 + c8 * 8];
            }
        }
        __syncthreads();
        if constexpr (A32) {
#pragma unroll
            for (int i = 0; i < 4; ++i) {
                int idx = i * 256 + t, row = idx >> 3, c4 = idx & 7;
                uint2 p = { pack2(ra32[i].x, ra32[i].y), pack2(ra32[i].z, ra32[i].w) };
                *(uint2*)&As[row * 40 + c4 * 4] = p;
            }
        } else {
#pragma unroll
            for (int i = 0; i < 2; ++i) {
                int idx = i * 256 + t, row = idx >> 2, c8 = idx & 3;
                *(bf16x8*)&As[row * 40 + c8 * 8] = ra16[i];
            }
        }
        if constexpr (B32) {
#pragma unroll
            for (int i = 0; i < 4; ++i) {
                int idx = i * 256 + t, row = idx >> 3, c4 = idx & 7;
                uint2 p = { pack2(rb32[i].x, rb32[i].y), pack2(rb32[i].z, rb32[i].w) };
                *(uint2*)&Bs[row * 40 + c4 * 4] = p;
            }
        } else {
#pragma unroll
            for (int i = 0; i < 2; ++i) {
                int idx = i * 256 + t, row = idx >> 2, c8 = idx & 3;
                *(bf16x8*)&Bs[row * 40 + c8 * 8] = rb16[i];
            }
        }
        __syncthreads();
        bf16x8 af[4], bfr[4];
#pragma unroll
        for (int i = 0; i < 4; ++i) {
            af[i]  = *(const bf16x8*)&As[(wm * 64 + i * 16 + lr) * 40 + kc * 8];
            bfr[i] = *(const bf16x8*)&Bs[(wn * 64 + i * 16 + lr) * 40 + kc * 8];
        }
#pragma unroll
        for (int mi = 0; mi < 4; ++mi)
#pragma unroll
            for (int ni = 0; ni < 4; ++ni)
                acc[mi][ni] = __builtin_amdgcn_mfma_f32_16x16x32_bf16(af[mi], bfr[ni], acc[mi][ni], 0, 0, 0);
    }
    const int rb0 = kc * 4;
#pragma unroll
    for (int mi = 0; mi < 4; ++mi) {
#pragma unroll
        for (int ni = 0; ni < 4; ++ni) {
            int col = n0 + wn * 64 + ni * 16 + lr;
            float badd = HAS_BIAS ? bias[col] : 0.0f;
#pragma unroll
            for (int r = 0; r < 4; ++r) {
                int row = m0 + wm * 64 + mi * 16 + rb0 + r;
                size_t off = TRANS_C ? ((size_t)col * ldc + row) : ((size_t)row * ldc + col);
                if (C32) ((float*)Cp)[off] = acc[mi][ni][r] + badd;
                else     ((unsigned short*)Cp)[off] = f2bf(acc[mi][ni][r] + badd);
            }
        }
    }
}

__global__ __launch_bounds__(256, 2)
void attn_slow(unsigned short* __restrict__ qk, const unsigned short* __restrict__ vt) {
    __shared__ __align__(16) unsigned short Ks[64 * 136];
    __shared__ __align__(16) unsigned short Vs[128 * 72];
    __shared__ __align__(16) unsigned short Ps[4 * 32 * 72];
    const int t = threadIdx.x, lane = t & 63, w = t >> 6;
    const int h = blockIdx.y, q0 = blockIdx.x * 128;
    const int lr = lane & 15, kc = lane >> 4;
    const float scale = 0.08838834764831845f;

    bf16x8 aq[2][4];
#pragma unroll
    for (int mf = 0; mf < 2; ++mf)
#pragma unroll
        for (int ks = 0; ks < 4; ++ks)
            aq[mf][ks] = *(const bf16x8*)&qk[(size_t)(q0 + w * 32 + mf * 16 + lr) * 6144 + h * 128 + ks * 32 + kc * 8];

    f32x4 o[2][8] = {};
    float mst[2][4], lst[2][4];
#pragma unroll
    for (int mf = 0; mf < 2; ++mf)
#pragma unroll
        for (int r = 0; r < 4; ++r) { mst[mf][r] = -1e30f; lst[mf][r] = 0.0f; }

    unsigned short* Pw = &Ps[w * 32 * 72];

    for (int kb = 0; kb < 2048; kb += 64) {
        bf16x8 rk[4], rv[4];
#pragma unroll
        for (int i = 0; i < 4; ++i) {
            int idx = i * 256 + t;
            { int row = idx >> 4, c8 = idx & 15;
              rk[i] = *(const bf16x8*)&qk[(size_t)(kb + row) * 6144 + 3072 + h * 128 + c8 * 8]; }
            { int row = idx >> 3, c8 = idx & 7;
              rv[i] = *(const bf16x8*)&vt[(size_t)(h * 128 + row) * 2048 + kb + c8 * 8]; }
        }
        __syncthreads();
#pragma unroll
        for (int i = 0; i < 4; ++i) {
            int idx = i * 256 + t;
            { int row = idx >> 4, c8 = idx & 15; *(bf16x8*)&Ks[row * 136 + c8 * 8] = rk[i]; }
            { int row = idx >> 3, c8 = idx & 7;  *(bf16x8*)&Vs[row * 72 + c8 * 8] = rv[i]; }
        }
        __syncthreads();

        f32x4 s[2][4] = {};
#pragma unroll
        for (int nt = 0; nt < 4; ++nt) {
            int rkr = nt * 16 + lr;
#pragma unroll
            for (int ks = 0; ks < 4; ++ks) {
                bf16x8 bk = *(const bf16x8*)&Ks[rkr * 136 + (ks * 4 + kc) * 8];
#pragma unroll
                for (int mf = 0; mf < 2; ++mf)
                    s[mf][nt] = __builtin_amdgcn_mfma_f32_16x16x32_bf16(aq[mf][ks], bk, s[mf][nt], 0, 0, 0);
            }
        }
#pragma unroll
        for (int mf = 0; mf < 2; ++mf)
#pragma unroll
            for (int nt = 0; nt < 4; ++nt)
#pragma unroll
                for (int r = 0; r < 4; ++r) s[mf][nt][r] *= scale;

#pragma unroll
        for (int mf = 0; mf < 2; ++mf) {
#pragma unroll
            for (int r = 0; r < 4; ++r) {
                float vmax = fmaxf(fmaxf(s[mf][0][r], s[mf][1][r]), fmaxf(s[mf][2][r], s[mf][3][r]));
#pragma unroll
                for (int off = 8; off >= 1; off >>= 1) vmax = fmaxf(vmax, __shfl_xor(vmax, off));
                float mn = fmaxf(mst[mf][r], vmax);
                float al = __expf(mst[mf][r] - mn);
                mst[mf][r] = mn;
                float ps = 0.0f;
#pragma unroll
                for (int nt = 0; nt < 4; ++nt) {
                    float p = __expf(s[mf][nt][r] - mn);
                    s[mf][nt][r] = p;
                    ps += p;
                }
#pragma unroll
                for (int off = 8; off >= 1; off >>= 1) ps += __shfl_xor(ps, off);
                lst[mf][r] = lst[mf][r] * al + ps;
#pragma unroll
                for (int dt = 0; dt < 8; ++dt) o[mf][dt][r] *= al;
            }
        }

#pragma unroll
        for (int mf = 0; mf < 2; ++mf)
#pragma unroll
            for (int nt = 0; nt < 4; ++nt)
#pragma unroll
                for (int r = 0; r < 4; ++r)
                    Pw[(mf * 16 + kc * 4 + r) * 72 + nt * 16 + lr] = f2bf(s[mf][nt][r]);

#pragma unroll
        for (int ks2 = 0; ks2 < 2; ++ks2) {
            bf16x8 ap[2];
#pragma unroll
            for (int mf = 0; mf < 2; ++mf)
                ap[mf] = *(const bf16x8*)&Pw[(mf * 16 + lr) * 72 + (ks2 * 4 + kc) * 8];
#pragma unroll
            for (int dt = 0; dt < 8; ++dt) {
                bf16x8 bv = *(const bf16x8*)&Vs[(dt * 16 + lr) * 72 + (ks2 * 4 + kc) * 8];
#pragma unroll
                for (int mf = 0; mf < 2; ++mf)
                    o[mf][dt] = __builtin_amdgcn_mfma_f32_16x16x32_bf16(ap[mf], bv, o[mf][dt], 0, 0, 0);
            }
        }
        __syncthreads();
    }

#pragma unroll
    for (int mf = 0; mf < 2; ++mf)
#pragma unroll
        for (int dt = 0; dt < 8; ++dt)
#pragma unroll
            for (int r = 0; r < 4; ++r) {
                int row = q0 + w * 32 + mf * 16 + kc * 4 + r;
                qk[(size_t)row * 6144 + h * 128 + dt * 16 + lr] = f2bf(o[mf][dt][r] / lst[mf][r]);
            }
}

__global__ void fill_two(float* p, int n) {
    int i = blockIdx.x * 256 + threadIdx.x;
    if (i < n) p[i] = 2.0f;
}

// ---------------------------------------------------------------------------
// Fast path (ws >= 120 MiB), shorts offsets:
//   xb 0 | wqkvb 6291456 | wprojb 34603008 | qk 44040192 | vt 56623104
// Slow path: round-4 layout (qk @0, vt @12582912), peak 36 MiB.
// ---------------------------------------------------------------------------
extern "C" void kernel_launch(void* const* d_in, const int* in_sizes, int n_in,
                              void* d_out, int out_size, void* d_ws, size_t ws_size,
                              hipStream_t stream) {
    const float* x       = (const float*)d_in[0];
    const float* pe      = (const float*)d_in[1];
    const float* w_qkv   = (const float*)d_in[2];
    const float* q_scale = (const float*)d_in[3];
    const float* k_scale = (const float*)d_in[4];
    const float* w_proj  = (const float*)d_in[5];
    const float* b_proj  = (const float*)d_in[6];
    float* out = (float*)d_out;

    if (ws_size >= 125829120ull) {           // ---- fast path ----
        unsigned short* ws     = (unsigned short*)d_ws;
        unsigned short* xb     = ws;
        unsigned short* wqkvb  = ws + 6291456;
        unsigned short* wprojb = ws + 34603008;
        unsigned short* qk     = ws + 44040192;
        unsigned short* vt     = ws + 56623104;

        cvt_bf16<<<3072, 256, 0, stream>>>((const float4*)x, (uint4*)xb, 786432);
        cvt_bf16<<<13824, 256, 0, stream>>>((const float4*)w_qkv, (uint4*)wqkvb, 3538944);
        cvt_bf16<<<4608, 256, 0, stream>>>((const float4*)w_proj, (uint4*)wprojb, 1179648);

        gemm_qkv<<<dim3(72, 16), 256, 0, stream>>>(xb, wqkvb, qk, vt);
        norm_rope<<<24576, 256, 0, stream>>>(qk, pe, q_scale, k_scale);
        attn2<<<dim3(24, 32), 256, 0, stream>>>(qk, vt);
        gemm_proj<<<dim3(24, 16), 256, 0, stream>>>(qk, wprojb, b_proj, out);
        return;
    }

    if (ws_size < 37748736ull) {             // ---- can't run at all ----
        fill_two<<<(6291456 + 255) / 256, 256, 0, stream>>>(out, 6291456);
        return;
    }

    // ---- slow path (round 4, proven) ----
    unsigned short* qk = (unsigned short*)d_ws;
    unsigned short* vt = qk + 12582912;

    gemm_bt<true, true, false, false, false><<<dim3(16, 48), 256, 0, stream>>>(
        x, w_qkv, nullptr, qk, 2048, 6144, 3072, 3072, 6144);
    norm_rope<<<24576, 256, 0, stream>>>(qk, pe, q_scale, k_scale);
    gemm_bt<true, true, false, false, true><<<dim3(16, 24), 256, 0, stream>>>(
        x, w_qkv + (size_t)6144 * 3072, nullptr, vt, 2048, 3072, 3072, 3072, 2048);
    attn_slow<<<dim3(16, 24), 256, 0, stream>>>(qk, vt);
    gemm_bt<false, true, true, true, false><<<dim3(16, 24), 256, 0, stream>>>(
        qk, w_proj, b_proj, out, 2048, 3072, 3072, 6144, 3072);
}